// Round 1
// baseline (199.259 us; speedup 1.0000x reference)
//
#include <hip/hip_runtime.h>

typedef unsigned short u16;
typedef unsigned int u32;

typedef __attribute__((ext_vector_type(8))) short short8;
typedef __attribute__((ext_vector_type(4))) float f32x4;

#define DEV static __device__ __forceinline__

// f32 -> bf16 round-to-nearest-even
DEV u16 f2bf(float f) {
    u32 u = __float_as_uint(f);
    u += 0x7fffu + ((u >> 16) & 1u);
    return (u16)(u >> 16);
}
DEV float bflo(u32 u) { return __uint_as_float(u << 16); }
DEV float bfhi(u32 u) { return __uint_as_float(u & 0xffff0000u); }
DEV u32 pack2(float a, float b) { return (u32)f2bf(a) | ((u32)f2bf(b) << 16); }

// ---------------------------------------------------------------------------
// Weight transpose + f32->bf16: W[k][n] (512x512 row-major) -> Wt[n][k] bf16.
// Both MFMA operands need K lane-contiguous, so B must be staged n-major.
// ---------------------------------------------------------------------------
__global__ __launch_bounds__(256) void wtrans_kernel(
    const float* __restrict__ Wq, const float* __restrict__ Wk,
    const float* __restrict__ Wv, const float* __restrict__ Wo,
    u16* __restrict__ out)
{
    __shared__ float tile[32][33];
    const float* W = (blockIdx.z == 0) ? Wq : (blockIdx.z == 1) ? Wk
                   : (blockIdx.z == 2) ? Wv : Wo;
    u16* Wt = out + (size_t)blockIdx.z * 512 * 512;
    const int n0 = blockIdx.x * 32, k0 = blockIdx.y * 32;
    const int c = threadIdx.x & 31, r0 = threadIdx.x >> 5;
#pragma unroll
    for (int i = 0; i < 4; ++i) {
        int r = r0 + i * 8;
        tile[r][c] = W[(size_t)(k0 + r) * 512 + (n0 + c)];  // coalesced rows
    }
    __syncthreads();
#pragma unroll
    for (int i = 0; i < 4; ++i) {
        int r = r0 + i * 8;
        Wt[(size_t)(n0 + r) * 512 + (k0 + c)] = f2bf(tile[c][r]);  // coalesced k
    }
}

// ---------------------------------------------------------------------------
// GEMM body: C[M=8192][512] = A[8192][512] @ W[512][512] + bias.
// A f32 or bf16; W given as Wt[n][k] bf16; out f32 or bf16.
// Tile 128x64, BK=32, 256 threads = 4 waves (2x2), per-wave 64x32 (acc[4][2]).
// XOR swizzle ((row&7)<<4) on every 16B LDS unit, applied identically on
// write and read -> bijective, bank-spread ds_read_b128.
// ---------------------------------------------------------------------------
template<bool A_F32, bool OUT_F32>
DEV void gemm_body(const void* __restrict__ Aptr, const u16* __restrict__ Wt,
                   const float* __restrict__ bias, void* __restrict__ Cptr,
                   int bm, int bn)
{
    constexpr int LK = 512;
    __shared__ u16 As[128 * 32];
    __shared__ u16 Bs[64 * 32];
    char* AsB = (char*)As;
    char* BsB = (char*)Bs;

    const int m0 = bm * 128, n0 = bn * 64;
    const int tid = threadIdx.x;
    const int lane = tid & 63;
    const int wave = tid >> 6;
    const int wr = wave >> 1, wc = wave & 1;
    const int l15 = lane & 15, l4 = lane >> 4;

    const f32x4 fzero = {0.f, 0.f, 0.f, 0.f};
    f32x4 acc[4][2];
#pragma unroll
    for (int i = 0; i < 4; ++i)
#pragma unroll
        for (int j = 0; j < 2; ++j) acc[i][j] = fzero;

    const int arow = tid >> 1, ahalf = tid & 1;  // A: 128 rows x 2 halves of 16
    const int brow = tid >> 2, bq4 = tid & 3;    // B: 64 rows x 4 chunks of 8

    for (int k0 = 0; k0 < LK; k0 += 32) {
        uint4 aw0, aw1;
        if (A_F32) {
            const float4* A = (const float4*)((const float*)Aptr +
                              (size_t)(m0 + arow) * LK + k0 + ahalf * 16);
            float4 v0 = A[0], v1 = A[1], v2 = A[2], v3 = A[3];
            aw0.x = pack2(v0.x, v0.y); aw0.y = pack2(v0.z, v0.w);
            aw0.z = pack2(v1.x, v1.y); aw0.w = pack2(v1.z, v1.w);
            aw1.x = pack2(v2.x, v2.y); aw1.y = pack2(v2.z, v2.w);
            aw1.z = pack2(v3.x, v3.y); aw1.w = pack2(v3.z, v3.w);
        } else {
            const uint4* A = (const uint4*)((const u16*)Aptr +
                             (size_t)(m0 + arow) * LK + k0 + ahalf * 16);
            aw0 = A[0]; aw1 = A[1];
        }
        const uint4 bw = *(const uint4*)(Wt + (size_t)(n0 + brow) * LK + k0 + bq4 * 8);

        {
            const int abase = arow * 64 + ahalf * 32;
            const int asw = (arow & 7) << 4;
            *(uint4*)(AsB + ((abase) ^ asw)) = aw0;
            *(uint4*)(AsB + ((abase + 16) ^ asw)) = aw1;
            const int bbase = brow * 64 + bq4 * 16;
            *(uint4*)(BsB + (bbase ^ ((brow & 7) << 4))) = bw;
        }
        __syncthreads();

        short8 af[4], bfr[2];
#pragma unroll
        for (int mi = 0; mi < 4; ++mi) {
            const int row = wr * 64 + mi * 16 + l15;
            af[mi] = *(const short8*)(AsB + ((row * 64 + l4 * 16) ^ ((row & 7) << 4)));
        }
#pragma unroll
        for (int ni = 0; ni < 2; ++ni) {
            const int row = wc * 32 + ni * 16 + l15;
            bfr[ni] = *(const short8*)(BsB + ((row * 64 + l4 * 16) ^ ((row & 7) << 4)));
        }
#pragma unroll
        for (int mi = 0; mi < 4; ++mi)
#pragma unroll
            for (int ni = 0; ni < 2; ++ni)
                acc[mi][ni] = __builtin_amdgcn_mfma_f32_16x16x32_bf16(
                    af[mi], bfr[ni], acc[mi][ni], 0, 0, 0);
        __syncthreads();
    }

    // epilogue: C/D layout col=lane&15, row=(lane>>4)*4+reg  [m89/m91 verified]
#pragma unroll
    for (int ni = 0; ni < 2; ++ni) {
        const int n = n0 + wc * 32 + ni * 16 + l15;
        const float bv = bias[n];
#pragma unroll
        for (int mi = 0; mi < 4; ++mi) {
            const int mb = m0 + wr * 64 + mi * 16 + l4 * 4;
#pragma unroll
            for (int r = 0; r < 4; ++r) {
                const float v = acc[mi][ni][r] + bv;
                if (OUT_F32)
                    ((float*)Cptr)[(size_t)(mb + r) * 512 + n] = v;
                else
                    ((u16*)Cptr)[(size_t)(mb + r) * 512 + n] = f2bf(v);
            }
        }
    }
}

// XCD-locality remap: 8 consecutive-id blocks (one per XCD via round-robin)
// get distinct bm; the 8 bn-blocks sharing a bm land on ONE xcd (same id%8).
DEV void remap_block(int id, int& bm, int& bn)
{
    bm = (id & 7) * 8 + ((id >> 3) & 7);  // [0,64)
    bn = id >> 6;                         // [0,8)
}

__global__ __launch_bounds__(256) void gemm_qkv_kernel(
    const float* __restrict__ q_in, const float* __restrict__ k_in,
    const float* __restrict__ v_in, const u16* __restrict__ Wt3,
    const float* __restrict__ bq, const float* __restrict__ bk,
    const float* __restrict__ bv,
    u16* __restrict__ Qo, u16* __restrict__ Ko, u16* __restrict__ Vo)
{
    const int mat = blockIdx.y;
    const float* A = (mat == 0) ? q_in : (mat == 1) ? k_in : v_in;
    const u16* W = Wt3 + (size_t)mat * 512 * 512;
    const float* bias = (mat == 0) ? bq : (mat == 1) ? bk : bv;
    u16* C = (mat == 0) ? Qo : (mat == 1) ? Ko : Vo;
    int bm, bn; remap_block(blockIdx.x, bm, bn);
    gemm_body<true, false>(A, W, bias, C, bm, bn);
}

__global__ __launch_bounds__(256) void gemm_out_kernel(
    const u16* __restrict__ Xb, const u16* __restrict__ Wto,
    const float* __restrict__ bo, float* __restrict__ out)
{
    int bm, bn; remap_block(blockIdx.x, bm, bn);
    gemm_body<false, true>(Xb, Wto, bo, out, bm, bn);
}

// ---------------------------------------------------------------------------
// Banded attention, window 31 (restrict hard-coded; r2=15), zero-padded edges.
// Zero-padding is semantic: pad positions contribute score EXACTLY 0 and
// participate in the softmax (matches the nn.Unfold reference path).
// One thread per (b,h,t); 128 t's per block; K/V window staged swizzled in LDS.
// Online softmax (no score array -> no scratch), mask applied post-softmax.
// ---------------------------------------------------------------------------
__global__ __launch_bounds__(128) void attn_kernel(
    const u16* __restrict__ Qb, const u16* __restrict__ Kb,
    const u16* __restrict__ Vb, const int* __restrict__ mask,
    u16* __restrict__ Xb)
{
    constexpr int TB = 128, R2 = 15, RW = 31, WR = TB + 2 * R2;  // WR=158
    __shared__ u16 Ks[WR * 64];
    __shared__ u16 Vs[WR * 64];
    char* KsB = (char*)Ks;
    char* VsB = (char*)Vs;
    const int tid = threadIdx.x;
    const int blk = blockIdx.x;              // ((b*8 + h)*16 + tb)
    const int tb = blk & 15, h = (blk >> 4) & 7, b = blk >> 7;
    const int t0 = tb * TB;
    const size_t hbase = (size_t)b * (2048 * 512) + h * 64;

    // stage K,V window rows [t0-15, t0+142], zero-filled outside [0,T)
    for (int u = tid; u < WR * 8; u += 128) {
        const int r = u >> 3, c = u & 7;
        const int g = t0 - R2 + r;
        uint4 kv = make_uint4(0, 0, 0, 0), vv = make_uint4(0, 0, 0, 0);
        if (g >= 0 && g < 2048) {
            const size_t off = hbase + (size_t)g * 512 + c * 8;
            kv = *(const uint4*)(Kb + off);
            vv = *(const uint4*)(Vb + off);
        }
        const int addr = r * 128 + ((c * 16) ^ ((r & 7) << 4));
        *(uint4*)(KsB + addr) = kv;
        *(uint4*)(VsB + addr) = vv;
    }
    __syncthreads();

    const int t = t0 + tid;
    float q[64];
    {
        const uint4* qp = (const uint4*)(Qb + hbase + (size_t)t * 512);
#pragma unroll
        for (int c = 0; c < 8; ++c) {
            const uint4 u = qp[c];
            q[c*8+0] = bflo(u.x); q[c*8+1] = bfhi(u.x);
            q[c*8+2] = bflo(u.y); q[c*8+3] = bfhi(u.y);
            q[c*8+4] = bflo(u.z); q[c*8+5] = bfhi(u.z);
            q[c*8+6] = bflo(u.w); q[c*8+7] = bfhi(u.w);
        }
    }
    float x[64];
#pragma unroll
    for (int d = 0; d < 64; ++d) x[d] = 0.f;
    float m = -1e30f, sum = 0.f;

#pragma unroll 1
    for (int j = 0; j < RW; ++j) {
        const int row = tid + j;                 // LDS row for key index t-15+j
        const int rb = row * 128, sw = (row & 7) << 4;
        uint4 kv[8];
#pragma unroll
        for (int c = 0; c < 8; ++c)
            kv[c] = *(const uint4*)(KsB + rb + ((c * 16) ^ sw));
        float a0 = 0.f, a1 = 0.f, a2 = 0.f, a3 = 0.f;
#pragma unroll
        for (int c = 0; c < 8; ++c) {
            a0 += q[c*8+0] * bflo(kv[c].x) + q[c*8+1] * bfhi(kv[c].x);
            a1 += q[c*8+2] * bflo(kv[c].y) + q[c*8+3] * bfhi(kv[c].y);
            a2 += q[c*8+4] * bflo(kv[c].z) + q[c*8+5] * bfhi(kv[c].z);
            a3 += q[c*8+6] * bflo(kv[c].w) + q[c*8+7] * bfhi(kv[c].w);
        }
        const float s = ((a0 + a1) + (a2 + a3)) * 0.125f;  // 1/sqrt(64)
        if (s > m) {                                        // online rescale
            const float sc = __expf(m - s);
            sum *= sc;
#pragma unroll
            for (int d = 0; d < 64; ++d) x[d] *= sc;
            m = s;
        }
        const float w = __expf(s - m);
        sum += w;
        uint4 vv[8];
#pragma unroll
        for (int c = 0; c < 8; ++c)
            vv[c] = *(const uint4*)(VsB + rb + ((c * 16) ^ sw));
#pragma unroll
        for (int c = 0; c < 8; ++c) {
            x[c*8+0] += w * bflo(vv[c].x); x[c*8+1] += w * bfhi(vv[c].x);
            x[c*8+2] += w * bflo(vv[c].y); x[c*8+3] += w * bfhi(vv[c].y);
            x[c*8+4] += w * bflo(vv[c].z); x[c*8+5] += w * bfhi(vv[c].z);
            x[c*8+6] += w * bflo(vv[c].w); x[c*8+7] += w * bfhi(vv[c].w);
        }
    }
    float inv = 1.0f / sum;                 // sum>0 always (pad scores = 0)
    if (mask[b * 2048 + t] == 0) inv = 0.f; // post-softmax mask
    u16* xp = Xb + hbase + (size_t)t * 512;
#pragma unroll
    for (int c = 0; c < 8; ++c) {
        uint4 o;
        o.x = pack2(x[c*8+0] * inv, x[c*8+1] * inv);
        o.y = pack2(x[c*8+2] * inv, x[c*8+3] * inv);
        o.z = pack2(x[c*8+4] * inv, x[c*8+5] * inv);
        o.w = pack2(x[c*8+6] * inv, x[c*8+7] * inv);
        *(uint4*)(xp + c * 8) = o;
    }
}

// ---------------------------------------------------------------------------
extern "C" void kernel_launch(void* const* d_in, const int* in_sizes, int n_in,
                              void* d_out, int out_size, void* d_ws, size_t ws_size,
                              hipStream_t stream)
{
    const float* query = (const float*)d_in[0];
    const float* key   = (const float*)d_in[1];
    const float* value = (const float*)d_in[2];
    const int*   mask  = (const int*)d_in[3];
    // d_in[4] = restrict (=31, hard-coded in attn_kernel)
    const float* Wq = (const float*)d_in[5];
    const float* bq = (const float*)d_in[6];
    const float* Wk = (const float*)d_in[7];
    const float* bk = (const float*)d_in[8];
    const float* Wv = (const float*)d_in[9];
    const float* bv = (const float*)d_in[10];
    const float* Wo = (const float*)d_in[11];
    const float* bo = (const float*)d_in[12];

    // ws layout (bf16 units): Wt[4*512*512] | Q | K | V | X  (each 8192*512)
    u16* wsp = (u16*)d_ws;
    u16* Wt  = wsp;
    u16* Qb  = wsp + 4 * 512 * 512;
    u16* Kb  = Qb + 8192 * 512;
    u16* Vb  = Kb + 8192 * 512;
    u16* Xb  = Vb + 8192 * 512;
    (void)in_sizes; (void)n_in; (void)out_size; (void)ws_size;

    wtrans_kernel<<<dim3(16, 16, 4), 256, 0, stream>>>(Wq, Wk, Wv, Wo, Wt);
    gemm_qkv_kernel<<<dim3(512, 3), 256, 0, stream>>>(
        query, key, value, Wt, bq, bk, bv, Qb, Kb, Vb);
    attn_kernel<<<512, 128, 0, stream>>>(Qb, Kb, Vb, mask, Xb);
    gemm_out_kernel<<<512, 256, 0, stream>>>(Xb, Wt + 3 * 512 * 512, bo,
                                             (float*)d_out);
}

// Round 2
// 185.465 us; speedup vs baseline: 1.0744x; 1.0744x over previous
//
#include <hip/hip_runtime.h>

typedef unsigned short u16;
typedef unsigned int u32;

typedef __attribute__((ext_vector_type(8))) short short8;
typedef __attribute__((ext_vector_type(4))) float f32x4;

#define DEV static __device__ __forceinline__
#define GLOBAL_AS __attribute__((address_space(1)))
#define LDS_AS __attribute__((address_space(3)))

// f32 -> bf16 round-to-nearest-even
DEV u16 f2bf(float f) {
    u32 u = __float_as_uint(f);
    u += 0x7fffu + ((u >> 16) & 1u);
    return (u16)(u >> 16);
}
DEV float bflo(u32 u) { return __uint_as_float(u << 16); }
DEV float bfhi(u32 u) { return __uint_as_float(u & 0xffff0000u); }
DEV u32 pack2(float a, float b) { return (u32)f2bf(a) | ((u32)f2bf(b) << 16); }

// async global->LDS, 16 bytes per lane (dest = wave-uniform base + lane*16)
DEV void gload16(const u16* g, u16* l) {
    __builtin_amdgcn_global_load_lds((const GLOBAL_AS u32*)(const void*)g,
                                     (LDS_AS u32*)(void*)l, 16, 0, 0);
}

// ---------------------------------------------------------------------------
// f32 -> bf16 elementwise convert for the three input activations.
// Memory-bound; float4 x2 loads, uint4 store (G13).
// ---------------------------------------------------------------------------
__global__ __launch_bounds__(256) void cvt_kernel(
    const float* __restrict__ q, const float* __restrict__ k,
    const float* __restrict__ v, u16* __restrict__ oq,
    u16* __restrict__ ok, u16* __restrict__ ov)
{
    const float* src = (blockIdx.y == 0) ? q : (blockIdx.y == 1) ? k : v;
    u16* dst = (blockIdx.y == 0) ? oq : (blockIdx.y == 1) ? ok : ov;
    const int NCH = 8192 * 512 / 8;  // 524288 chunks of 8 floats
    for (int i = blockIdx.x * 256 + threadIdx.x; i < NCH; i += gridDim.x * 256) {
        const float4* p = (const float4*)(src + (size_t)i * 8);
        const float4 a = p[0], b = p[1];
        uint4 o;
        o.x = pack2(a.x, a.y); o.y = pack2(a.z, a.w);
        o.z = pack2(b.x, b.y); o.w = pack2(b.z, b.w);
        *(uint4*)(dst + (size_t)i * 8) = o;
    }
}

// ---------------------------------------------------------------------------
// Weight transpose + f32->bf16: W[k][n] (512x512 row-major) -> Wt[n][k] bf16.
// ---------------------------------------------------------------------------
__global__ __launch_bounds__(256) void wtrans_kernel(
    const float* __restrict__ Wq, const float* __restrict__ Wk,
    const float* __restrict__ Wv, const float* __restrict__ Wo,
    u16* __restrict__ out)
{
    __shared__ float tile[32][33];
    const float* W = (blockIdx.z == 0) ? Wq : (blockIdx.z == 1) ? Wk
                   : (blockIdx.z == 2) ? Wv : Wo;
    u16* Wt = out + (size_t)blockIdx.z * 512 * 512;
    const int n0 = blockIdx.x * 32, k0 = blockIdx.y * 32;
    const int c = threadIdx.x & 31, r0 = threadIdx.x >> 5;
#pragma unroll
    for (int i = 0; i < 4; ++i) {
        int r = r0 + i * 8;
        tile[r][c] = W[(size_t)(k0 + r) * 512 + (n0 + c)];
    }
    __syncthreads();
#pragma unroll
    for (int i = 0; i < 4; ++i) {
        int r = r0 + i * 8;
        Wt[(size_t)(n0 + r) * 512 + (k0 + c)] = f2bf(tile[c][r]);
    }
}

// ---------------------------------------------------------------------------
// GEMM: C[8192][512] = A[8192][512](bf16) @ Wt[n][k](bf16) + bias.
// m97 structure: 128x128 tile, BK=64, 4 waves (2x2), acc[4][4],
// global_load_lds width=16, 2 barriers per K-step.
// Swizzle (rule #21): LDS dest linear; SOURCE 16B-chunk index cc^=(row&7);
// same XOR on ds_read. ds_read_b128 then spreads over all bank quads.
// ---------------------------------------------------------------------------
template<bool OUT_F32>
DEV void gemm_body(const u16* __restrict__ A, const u16* __restrict__ Wt,
                   const float* __restrict__ bias, void* __restrict__ Cptr,
                   int bm, int bn)
{
    __shared__ u16 As[128 * 64];
    __shared__ u16 Bs[128 * 64];
    const char* AsB = (const char*)As;
    const char* BsB = (const char*)Bs;

    const int tid = threadIdx.x;
    const int lane = tid & 63;
    const int wave = tid >> 6;
    const int wr = wave >> 1, wc = wave & 1;
    const int l15 = lane & 15, l4 = lane >> 4;
    const int m0 = bm * 128, n0 = bn * 128;

    const f32x4 fzero = {0.f, 0.f, 0.f, 0.f};
    f32x4 acc[4][4];
#pragma unroll
    for (int i = 0; i < 4; ++i)
#pragma unroll
        for (int j = 0; j < 4; ++j) acc[i][j] = fzero;

    for (int k0 = 0; k0 < 512; k0 += 64) {
        __syncthreads();  // previous-step reads done before overwrite
#pragma unroll
        for (int i = 0; i < 4; ++i) {
            const int chunk = i * 256 + tid;          // [0,1024): 16B units
            const int row = chunk >> 3;               // [0,128)
            const int ccs = (chunk & 7) ^ (row & 7);  // pre-swizzled source col
            gload16(A + (size_t)(m0 + row) * 512 + k0 + ccs * 8, &As[chunk * 8]);
            gload16(Wt + (size_t)(n0 + row) * 512 + k0 + ccs * 8, &Bs[chunk * 8]);
        }
        __syncthreads();  // compiler drains vmcnt(0) here

#pragma unroll
        for (int kk = 0; kk < 2; ++kk) {
            short8 af[4], bf[4];
#pragma unroll
            for (int mi = 0; mi < 4; ++mi) {
                const int row = wr * 64 + mi * 16 + l15;
                const int cc = (kk * 4 + l4) ^ (row & 7);
                af[mi] = *(const short8*)(AsB + row * 128 + cc * 16);
            }
#pragma unroll
            for (int ni = 0; ni < 4; ++ni) {
                const int row = wc * 64 + ni * 16 + l15;
                const int cc = (kk * 4 + l4) ^ (row & 7);
                bf[ni] = *(const short8*)(BsB + row * 128 + cc * 16);
            }
#pragma unroll
            for (int mi = 0; mi < 4; ++mi)
#pragma unroll
                for (int ni = 0; ni < 4; ++ni)
                    acc[mi][ni] = __builtin_amdgcn_mfma_f32_16x16x32_bf16(
                        af[mi], bf[ni], acc[mi][ni], 0, 0, 0);
        }
    }

    // epilogue: C/D layout col=lane&15, row=(lane>>4)*4+reg  [m89/m91]
#pragma unroll
    for (int ni = 0; ni < 4; ++ni) {
        const int n = n0 + wc * 64 + ni * 16 + l15;
        const float bv = bias[n];
#pragma unroll
        for (int mi = 0; mi < 4; ++mi) {
            const int mb = m0 + wr * 64 + mi * 16 + l4 * 4;
#pragma unroll
            for (int r = 0; r < 4; ++r) {
                const float v = acc[mi][ni][r] + bv;
                if (OUT_F32)
                    ((float*)Cptr)[(size_t)(mb + r) * 512 + n] = v;
                else
                    ((u16*)Cptr)[(size_t)(mb + r) * 512 + n] = f2bf(v);
            }
        }
    }
}

// XCD swizzle: 256 blocks, 8 XCDs, 32 blocks/XCD contiguous (bijective).
// Within an XCD, bn (4) cycles fastest -> bm panel (128x512 bf16 = 128 KB)
// and full B (0.5 MB) both L2-resident.
DEV void remap_block(int id, int& bm, int& bn)
{
    const int swz = (id & 7) * 32 + (id >> 3);  // [0,256)
    bn = swz & 3;
    bm = swz >> 2;
}

__global__ __launch_bounds__(256) void gemm_qkv_kernel(
    const u16* __restrict__ qc, const u16* __restrict__ kc,
    const u16* __restrict__ vc, const u16* __restrict__ Wt3,
    const float* __restrict__ bq, const float* __restrict__ bk,
    const float* __restrict__ bv,
    u16* __restrict__ Qo, u16* __restrict__ Ko, u16* __restrict__ Vo)
{
    const int mat = blockIdx.y;
    const u16* A = (mat == 0) ? qc : (mat == 1) ? kc : vc;
    const u16* W = Wt3 + (size_t)mat * 512 * 512;
    const float* bias = (mat == 0) ? bq : (mat == 1) ? bk : bv;
    u16* C = (mat == 0) ? Qo : (mat == 1) ? Ko : Vo;
    int bm, bn; remap_block(blockIdx.x, bm, bn);
    gemm_body<false>(A, W, bias, C, bm, bn);
}

__global__ __launch_bounds__(256) void gemm_out_kernel(
    const u16* __restrict__ Xb, const u16* __restrict__ Wto,
    const float* __restrict__ bo, float* __restrict__ out)
{
    int bm, bn; remap_block(blockIdx.x, bm, bn);
    gemm_body<true>(Xb, Wto, bo, out, bm, bn);
}

// ---------------------------------------------------------------------------
// Banded attention, window 31, zero-padded edges (pad scores = 0 participate
// in softmax, matching nn.Unfold). One thread per (b,h,t); K/V window staged
// swizzled in LDS; online softmax; mask applied post-softmax.
// ---------------------------------------------------------------------------
__global__ __launch_bounds__(128) void attn_kernel(
    const u16* __restrict__ Qb, const u16* __restrict__ Kb,
    const u16* __restrict__ Vb, const int* __restrict__ mask,
    u16* __restrict__ Xb)
{
    constexpr int TB = 128, R2 = 15, RW = 31, WR = TB + 2 * R2;  // WR=158
    __shared__ u16 Ks[WR * 64];
    __shared__ u16 Vs[WR * 64];
    char* KsB = (char*)Ks;
    char* VsB = (char*)Vs;
    const int tid = threadIdx.x;
    const int blk = blockIdx.x;              // ((b*8 + h)*16 + tb)
    const int tb = blk & 15, h = (blk >> 4) & 7, b = blk >> 7;
    const int t0 = tb * TB;
    const size_t hbase = (size_t)b * (2048 * 512) + h * 64;

    for (int u = tid; u < WR * 8; u += 128) {
        const int r = u >> 3, c = u & 7;
        const int g = t0 - R2 + r;
        uint4 kv = make_uint4(0, 0, 0, 0), vv = make_uint4(0, 0, 0, 0);
        if (g >= 0 && g < 2048) {
            const size_t off = hbase + (size_t)g * 512 + c * 8;
            kv = *(const uint4*)(Kb + off);
            vv = *(const uint4*)(Vb + off);
        }
        const int addr = r * 128 + ((c * 16) ^ ((r & 7) << 4));
        *(uint4*)(KsB + addr) = kv;
        *(uint4*)(VsB + addr) = vv;
    }
    __syncthreads();

    const int t = t0 + tid;
    float q[64];
    {
        const uint4* qp = (const uint4*)(Qb + hbase + (size_t)t * 512);
#pragma unroll
        for (int c = 0; c < 8; ++c) {
            const uint4 u = qp[c];
            q[c*8+0] = bflo(u.x); q[c*8+1] = bfhi(u.x);
            q[c*8+2] = bflo(u.y); q[c*8+3] = bfhi(u.y);
            q[c*8+4] = bflo(u.z); q[c*8+5] = bfhi(u.z);
            q[c*8+6] = bflo(u.w); q[c*8+7] = bfhi(u.w);
        }
    }
    float x[64];
#pragma unroll
    for (int d = 0; d < 64; ++d) x[d] = 0.f;
    float m = -1e30f, sum = 0.f;

#pragma unroll 1
    for (int j = 0; j < RW; ++j) {
        const int row = tid + j;
        const int rb = row * 128, sw = (row & 7) << 4;
        uint4 kv[8];
#pragma unroll
        for (int c = 0; c < 8; ++c)
            kv[c] = *(const uint4*)(KsB + rb + ((c * 16) ^ sw));
        float a0 = 0.f, a1 = 0.f, a2 = 0.f, a3 = 0.f;
#pragma unroll
        for (int c = 0; c < 8; ++c) {
            a0 += q[c*8+0] * bflo(kv[c].x) + q[c*8+1] * bfhi(kv[c].x);
            a1 += q[c*8+2] * bflo(kv[c].y) + q[c*8+3] * bfhi(kv[c].y);
            a2 += q[c*8+4] * bflo(kv[c].z) + q[c*8+5] * bfhi(kv[c].z);
            a3 += q[c*8+6] * bflo(kv[c].w) + q[c*8+7] * bfhi(kv[c].w);
        }
        const float s = ((a0 + a1) + (a2 + a3)) * 0.125f;  // 1/sqrt(64)
        if (s > m) {
            const float sc = __expf(m - s);
            sum *= sc;
#pragma unroll
            for (int d = 0; d < 64; ++d) x[d] *= sc;
            m = s;
        }
        const float w = __expf(s - m);
        sum += w;
        uint4 vv[8];
#pragma unroll
        for (int c = 0; c < 8; ++c)
            vv[c] = *(const uint4*)(VsB + rb + ((c * 16) ^ sw));
#pragma unroll
        for (int c = 0; c < 8; ++c) {
            x[c*8+0] += w * bflo(vv[c].x); x[c*8+1] += w * bfhi(vv[c].x);
            x[c*8+2] += w * bflo(vv[c].y); x[c*8+3] += w * bfhi(vv[c].y);
            x[c*8+4] += w * bflo(vv[c].z); x[c*8+5] += w * bfhi(vv[c].z);
            x[c*8+6] += w * bflo(vv[c].w); x[c*8+7] += w * bfhi(vv[c].w);
        }
    }
    float inv = 1.0f / sum;
    if (mask[b * 2048 + t] == 0) inv = 0.f;
    u16* xp = Xb + hbase + (size_t)t * 512;
#pragma unroll
    for (int c = 0; c < 8; ++c) {
        uint4 o;
        o.x = pack2(x[c*8+0] * inv, x[c*8+1] * inv);
        o.y = pack2(x[c*8+2] * inv, x[c*8+3] * inv);
        o.z = pack2(x[c*8+4] * inv, x[c*8+5] * inv);
        o.w = pack2(x[c*8+6] * inv, x[c*8+7] * inv);
        *(uint4*)(xp + c * 8) = o;
    }
}

// ---------------------------------------------------------------------------
extern "C" void kernel_launch(void* const* d_in, const int* in_sizes, int n_in,
                              void* d_out, int out_size, void* d_ws, size_t ws_size,
                              hipStream_t stream)
{
    const float* query = (const float*)d_in[0];
    const float* key   = (const float*)d_in[1];
    const float* value = (const float*)d_in[2];
    const int*   mask  = (const int*)d_in[3];
    // d_in[4] = restrict (=31, hard-coded)
    const float* Wq = (const float*)d_in[5];
    const float* bq = (const float*)d_in[6];
    const float* Wk = (const float*)d_in[7];
    const float* bk = (const float*)d_in[8];
    const float* Wv = (const float*)d_in[9];
    const float* bv = (const float*)d_in[10];
    const float* Wo = (const float*)d_in[11];
    const float* bo = (const float*)d_in[12];

    // ws (bf16 units): Wt[4*256K] | qc | kc | vc | Qb | Kb | Vb  (each 4M)
    // Xb aliases qc (qc is dead after gemm_qkv).  Total ~52.5 MB.
    constexpr size_t MSZ = (size_t)8192 * 512;
    u16* wsp = (u16*)d_ws;
    u16* Wt = wsp;
    u16* qc = wsp + 4 * 512 * 512;
    u16* kc = qc + MSZ;
    u16* vc = kc + MSZ;
    u16* Qb = vc + MSZ;
    u16* Kb = Qb + MSZ;
    u16* Vb = Kb + MSZ;
    u16* Xb = qc;  // alias
    (void)in_sizes; (void)n_in; (void)out_size; (void)ws_size;

    cvt_kernel<<<dim3(1024, 3), 256, 0, stream>>>(query, key, value, qc, kc, vc);
    wtrans_kernel<<<dim3(16, 16, 4), 256, 0, stream>>>(Wq, Wk, Wv, Wo, Wt);
    gemm_qkv_kernel<<<dim3(256, 3), 256, 0, stream>>>(
        qc, kc, vc, Wt, bq, bk, bv, Qb, Kb, Vb);
    attn_kernel<<<512, 128, 0, stream>>>(Qb, Kb, Vb, mask, Xb);
    gemm_out_kernel<<<256, 256, 0, stream>>>(Xb, Wt + 3 * 512 * 512, bo,
                                             (float*)d_out);
}

// Round 6
// 155.575 us; speedup vs baseline: 1.2808x; 1.1921x over previous
//
#include <hip/hip_runtime.h>

typedef unsigned short u16;
typedef unsigned int u32;

typedef __attribute__((ext_vector_type(8))) short short8;
typedef __attribute__((ext_vector_type(4))) float f32x4;

#define DEV static __device__ __forceinline__
#define GLOBAL_AS __attribute__((address_space(1)))
#define LDS_AS __attribute__((address_space(3)))

// f32 -> bf16 round-to-nearest-even
DEV u16 f2bf(float f) {
    u32 u = __float_as_uint(f);
    u += 0x7fffu + ((u >> 16) & 1u);
    return (u16)(u >> 16);
}
DEV float bflo(u32 u) { return __uint_as_float(u << 16); }
DEV float bfhi(u32 u) { return __uint_as_float(u & 0xffff0000u); }
DEV u32 pack2(float a, float b) { return (u32)f2bf(a) | ((u32)f2bf(b) << 16); }

// async global->LDS, 16 bytes per lane (dest = wave-uniform base + lane*16)
DEV void gload16(const u16* g, u16* l) {
    __builtin_amdgcn_global_load_lds((const GLOBAL_AS u32*)(const void*)g,
                                     (LDS_AS u32*)(void*)l, 16, 0, 0);
}

// ---------------------------------------------------------------------------
// f32 -> bf16 elementwise convert for the three input activations.
// ---------------------------------------------------------------------------
__global__ __launch_bounds__(256) void cvt_kernel(
    const float* __restrict__ q, const float* __restrict__ k,
    const float* __restrict__ v, u16* __restrict__ oq,
    u16* __restrict__ ok, u16* __restrict__ ov)
{
    const float* src = (blockIdx.y == 0) ? q : (blockIdx.y == 1) ? k : v;
    u16* dst = (blockIdx.y == 0) ? oq : (blockIdx.y == 1) ? ok : ov;
    const int NCH = 8192 * 512 / 8;
    for (int i = blockIdx.x * 256 + threadIdx.x; i < NCH; i += gridDim.x * 256) {
        const float4* p = (const float4*)(src + (size_t)i * 8);
        const float4 a = p[0], b = p[1];
        uint4 o;
        o.x = pack2(a.x, a.y); o.y = pack2(a.z, a.w);
        o.z = pack2(b.x, b.y); o.w = pack2(b.z, b.w);
        *(uint4*)(dst + (size_t)i * 8) = o;
    }
}

// ---------------------------------------------------------------------------
// Weight transpose + f32->bf16: W[k][n] (512x512 row-major) -> Wt[n][k] bf16.
// ---------------------------------------------------------------------------
__global__ __launch_bounds__(256) void wtrans_kernel(
    const float* __restrict__ Wq, const float* __restrict__ Wk,
    const float* __restrict__ Wv, const float* __restrict__ Wo,
    u16* __restrict__ out)
{
    __shared__ float tile[32][33];
    const float* W = (blockIdx.z == 0) ? Wq : (blockIdx.z == 1) ? Wk
                   : (blockIdx.z == 2) ? Wv : Wo;
    u16* Wt = out + (size_t)blockIdx.z * 512 * 512;
    const int n0 = blockIdx.x * 32, k0 = blockIdx.y * 32;
    const int c = threadIdx.x & 31, r0 = threadIdx.x >> 5;
#pragma unroll
    for (int i = 0; i < 4; ++i) {
        int r = r0 + i * 8;
        tile[r][c] = W[(size_t)(k0 + r) * 512 + (n0 + c)];
    }
    __syncthreads();
#pragma unroll
    for (int i = 0; i < 4; ++i) {
        int r = r0 + i * 8;
        Wt[(size_t)(n0 + r) * 512 + (k0 + c)] = f2bf(tile[c][r]);
    }
}

// ---------------------------------------------------------------------------
// GEMM: C[8192][512] = A[8192][512](bf16) @ Wt[n][k](bf16) + bias.
// m97 structure: 128x128 tile, BK=64, 4 waves (2x2), acc[4][4],
// global_load_lds width=16, swizzle per rule #21.
// ---------------------------------------------------------------------------
template<bool OUT_F32>
DEV void gemm_body(const u16* __restrict__ A, const u16* __restrict__ Wt,
                   const float* __restrict__ bias, void* __restrict__ Cptr,
                   int bm, int bn)
{
    __shared__ u16 As[128 * 64];
    __shared__ u16 Bs[128 * 64];
    const char* AsB = (const char*)As;
    const char* BsB = (const char*)Bs;

    const int tid = threadIdx.x;
    const int lane = tid & 63;
    const int wave = tid >> 6;
    const int wr = wave >> 1, wc = wave & 1;
    const int l15 = lane & 15, l4 = lane >> 4;
    const int m0 = bm * 128, n0 = bn * 128;

    const f32x4 fzero = {0.f, 0.f, 0.f, 0.f};
    f32x4 acc[4][4];
#pragma unroll
    for (int i = 0; i < 4; ++i)
#pragma unroll
        for (int j = 0; j < 4; ++j) acc[i][j] = fzero;

    for (int k0 = 0; k0 < 512; k0 += 64) {
        __syncthreads();
#pragma unroll
        for (int i = 0; i < 4; ++i) {
            const int chunk = i * 256 + tid;
            const int row = chunk >> 3;
            const int ccs = (chunk & 7) ^ (row & 7);
            gload16(A + (size_t)(m0 + row) * 512 + k0 + ccs * 8, &As[chunk * 8]);
            gload16(Wt + (size_t)(n0 + row) * 512 + k0 + ccs * 8, &Bs[chunk * 8]);
        }
        __syncthreads();

#pragma unroll
        for (int kk = 0; kk < 2; ++kk) {
            short8 af[4], bf[4];
#pragma unroll
            for (int mi = 0; mi < 4; ++mi) {
                const int row = wr * 64 + mi * 16 + l15;
                const int cc = (kk * 4 + l4) ^ (row & 7);
                af[mi] = *(const short8*)(AsB + row * 128 + cc * 16);
            }
#pragma unroll
            for (int ni = 0; ni < 4; ++ni) {
                const int row = wc * 64 + ni * 16 + l15;
                const int cc = (kk * 4 + l4) ^ (row & 7);
                bf[ni] = *(const short8*)(BsB + row * 128 + cc * 16);
            }
#pragma unroll
            for (int mi = 0; mi < 4; ++mi)
#pragma unroll
                for (int ni = 0; ni < 4; ++ni)
                    acc[mi][ni] = __builtin_amdgcn_mfma_f32_16x16x32_bf16(
                        af[mi], bf[ni], acc[mi][ni], 0, 0, 0);
        }
    }

#pragma unroll
    for (int ni = 0; ni < 4; ++ni) {
        const int n = n0 + wc * 64 + ni * 16 + l15;
        const float bv = bias[n];
#pragma unroll
        for (int mi = 0; mi < 4; ++mi) {
            const int mb = m0 + wr * 64 + mi * 16 + l4 * 4;
#pragma unroll
            for (int r = 0; r < 4; ++r) {
                const float v = acc[mi][ni][r] + bv;
                if (OUT_F32)
                    ((float*)Cptr)[(size_t)(mb + r) * 512 + n] = v;
                else
                    ((u16*)Cptr)[(size_t)(mb + r) * 512 + n] = f2bf(v);
            }
        }
    }
}

DEV void remap_block(int id, int& bm, int& bn)
{
    const int swz = (id & 7) * 32 + (id >> 3);
    bn = swz & 3;
    bm = swz >> 2;
}

__global__ __launch_bounds__(256) void gemm_qkv_kernel(
    const u16* __restrict__ qc, const u16* __restrict__ kc,
    const u16* __restrict__ vc, const u16* __restrict__ Wt3,
    const float* __restrict__ bq, const float* __restrict__ bk,
    const float* __restrict__ bv,
    u16* __restrict__ Qo, u16* __restrict__ Ko, u16* __restrict__ Vo)
{
    const int mat = blockIdx.y;
    const u16* A = (mat == 0) ? qc : (mat == 1) ? kc : vc;
    const u16* W = Wt3 + (size_t)mat * 512 * 512;
    const float* bias = (mat == 0) ? bq : (mat == 1) ? bk : bv;
    u16* C = (mat == 0) ? Qo : (mat == 1) ? Ko : Vo;
    int bm, bn; remap_block(blockIdx.x, bm, bn);
    gemm_body<false>(A, W, bias, C, bm, bn);
}

__global__ __launch_bounds__(256) void gemm_out_kernel(
    const u16* __restrict__ Xb, const u16* __restrict__ Wto,
    const float* __restrict__ bo, float* __restrict__ out)
{
    int bm, bn; remap_block(blockIdx.x, bm, bn);
    gemm_body<true>(Xb, Wto, bo, out, bm, bn);
}

// ---------------------------------------------------------------------------
// MFMA banded attention, window 31 (r2=15), zero-padded edges.
// Block: 128 q-rows, 4 waves x 32 rows. Per wave: 62-key window padded to 64.
// QK^T (16 mfma) -> band-masked wave-parallel softmax -> P(bf16) via LDS ->
// PV (16 mfma vs transposed V) -> in-register normalize -> coalesced store.
// Zero-padded edge keys give score exactly 0 and PARTICIPATE in softmax
// (matches nn.Unfold); outside-band slots are -inf (excluded).
// Vt row stride = 384 B (24 chunk slots): the swizzle cs = (cv&24)|((cv&7)^
// (d&7)) maps the partial third group cv in [16,20) onto cs in [16,24) --
// with a 320 B stride those writes overflowed into row d+1 (the round-2 bug).
// ---------------------------------------------------------------------------
__global__ __launch_bounds__(256) void attn_kernel(
    const u16* __restrict__ Qb, const u16* __restrict__ Kb,
    const u16* __restrict__ Vb, const int* __restrict__ mask,
    u16* __restrict__ Xb)
{
    constexpr int TB = 128, R2 = 15, WR = 160;  // 158 staged + 2 pad
    constexpr int VS = 384;                     // Vt row stride in bytes
    __shared__ u16 Ks[WR * 64];        // [kr][d] swizzled, 20 KB
    __shared__ u16 Qs[TB * 64];        // [r][d] swizzled, 16 KB; reused as P/O
    __shared__ u16 Vt[64 * (VS / 2)];  // [d][kr] swizzled, 24 KB
    char* KsB = (char*)Ks;
    char* QsB = (char*)Qs;
    char* VtB = (char*)Vt;

    const int tid = threadIdx.x;
    const int blk = blockIdx.x;              // ((b*8 + h)*16 + tb)
    const int tb = blk & 15, h = (blk >> 4) & 7, b = blk >> 7;
    const int T0 = tb * TB;
    const int G0 = T0 - R2;
    const size_t hbase = (size_t)b * (2048 * 512) + h * 64;

    // ---- stage K (row-major, swizzled) and V (transposed, swizzled) ----
    for (int u = tid; u < WR * 8; u += 256) {
        const int r = u >> 3, c = u & 7;
        const int g = G0 + r;
        uint4 kv = make_uint4(0, 0, 0, 0), vv = make_uint4(0, 0, 0, 0);
        if (g >= 0 && g < 2048) {
            const size_t off = hbase + (size_t)g * 512 + c * 8;
            kv = *(const uint4*)(Kb + off);
            vv = *(const uint4*)(Vb + off);
        }
        *(uint4*)(KsB + r * 128 + ((c ^ (r & 7)) << 4)) = kv;
        // scatter V transposed: element (kr=r, d=c*8+i) -> Vt[d][r]
        const int cv = r >> 3, relem = r & 7;
        const u16 vs[8] = {
            (u16)(vv.x & 0xffff), (u16)(vv.x >> 16),
            (u16)(vv.y & 0xffff), (u16)(vv.y >> 16),
            (u16)(vv.z & 0xffff), (u16)(vv.z >> 16),
            (u16)(vv.w & 0xffff), (u16)(vv.w >> 16)};
#pragma unroll
        for (int i = 0; i < 8; ++i) {
            const int d = c * 8 + i;
            const int cs = (cv & 24) | ((cv & 7) ^ (d & 7));
            *(u16*)(VtB + d * VS + cs * 16 + relem * 2) = vs[i];
        }
    }
    // ---- stage Q (row-major, swizzled) ----
    for (int u = tid; u < TB * 8; u += 256) {
        const int r = u >> 3, c = u & 7;
        const uint4 qv = *(const uint4*)(Qb + hbase + (size_t)(T0 + r) * 512 + c * 8);
        *(uint4*)(QsB + r * 128 + ((c ^ (r & 7)) << 4)) = qv;
    }
    __syncthreads();

    const int lane = tid & 63;
    const int w = tid >> 6;
    const int l15 = lane & 15, l4 = lane >> 4;
    const int wrow0 = w * 32;                 // wave's first q-row (block-local)
    char* Pw = QsB + wrow0 * 128;             // per-wave 4 KB P/O region

    // ---- QK^T ----
    short8 aq[2][2], bk_[4][2];
#pragma unroll
    for (int mt = 0; mt < 2; ++mt)
#pragma unroll
        for (int kk = 0; kk < 2; ++kk) {
            const int r = wrow0 + mt * 16 + l15;
            const int cc = (kk * 4 + l4) ^ (r & 7);
            aq[mt][kk] = *(const short8*)(QsB + r * 128 + cc * 16);
        }
#pragma unroll
    for (int nt = 0; nt < 4; ++nt)
#pragma unroll
        for (int kk = 0; kk < 2; ++kk) {
            const int kr = wrow0 + nt * 16 + l15;
            const int cc = (kk * 4 + l4) ^ (kr & 7);
            bk_[nt][kk] = *(const short8*)(KsB + kr * 128 + cc * 16);
        }
    const f32x4 fzero = {0.f, 0.f, 0.f, 0.f};
    f32x4 s[2][4];
#pragma unroll
    for (int mt = 0; mt < 2; ++mt)
#pragma unroll
        for (int nt = 0; nt < 4; ++nt) {
            s[mt][nt] = fzero;
#pragma unroll
            for (int kk = 0; kk < 2; ++kk)
                s[mt][nt] = __builtin_amdgcn_mfma_f32_16x16x32_bf16(
                    aq[mt][kk], bk_[nt][kk], s[mt][nt], 0, 0, 0);
        }

    // ---- band-masked softmax (rows r=mt*16+l4*4+reg; cols jj=nt*16+l15) ----
    float inv_[2][4];
#pragma unroll
    for (int mt = 0; mt < 2; ++mt) {
#pragma unroll
        for (int reg = 0; reg < 4; ++reg) {
            const int r = mt * 16 + l4 * 4 + reg;  // wave-local q-row
            float pv[4];
            float mx = -1e30f;
#pragma unroll
            for (int nt = 0; nt < 4; ++nt) {
                const int jj = nt * 16 + l15;
                float sv = s[mt][nt][reg] * 0.125f;     // 1/sqrt(64)
                sv = (jj >= r && jj <= r + 30) ? sv : -1e30f;
                pv[nt] = sv;
                mx = fmaxf(mx, sv);
            }
            mx = fmaxf(mx, __shfl_xor(mx, 1));
            mx = fmaxf(mx, __shfl_xor(mx, 2));
            mx = fmaxf(mx, __shfl_xor(mx, 4));
            mx = fmaxf(mx, __shfl_xor(mx, 8));
            float sum = 0.f;
#pragma unroll
            for (int nt = 0; nt < 4; ++nt) {
                const float p = __expf(pv[nt] - mx);
                pv[nt] = p;
                sum += p;
            }
            sum += __shfl_xor(sum, 1);
            sum += __shfl_xor(sum, 2);
            sum += __shfl_xor(sum, 4);
            sum += __shfl_xor(sum, 8);
            inv_[mt][reg] = 1.0f / sum;
            // write P (bf16) into per-wave region, A-frag swizzled layout
#pragma unroll
            for (int nt = 0; nt < 4; ++nt) {
                const int jj = nt * 16 + l15;
                const int cc = (jj >> 3) ^ (r & 7);
                *(u16*)(Pw + r * 128 + cc * 16 + (jj & 7) * 2) = f2bf(pv[nt]);
            }
        }
    }

    // ---- PV:  O[r][d] = P[r][jj] * Vt[d][jj] ----
    short8 pa[2][2], bv[4][2];
#pragma unroll
    for (int mt = 0; mt < 2; ++mt)
#pragma unroll
        for (int kk = 0; kk < 2; ++kk) {
            const int r = mt * 16 + l15;
            const int cc = (kk * 4 + l4) ^ (r & 7);
            pa[mt][kk] = *(const short8*)(Pw + r * 128 + cc * 16);
        }
#pragma unroll
    for (int dt = 0; dt < 4; ++dt)
#pragma unroll
        for (int kk = 0; kk < 2; ++kk) {
            const int d = dt * 16 + l15;
            const int c = w * 4 + kk * 4 + l4;        // key chunk in [0,20)
            const int cs = (c & 24) | ((c & 7) ^ (d & 7));
            bv[dt][kk] = *(const short8*)(VtB + d * VS + cs * 16);
        }
    f32x4 o[2][4];
#pragma unroll
    for (int mt = 0; mt < 2; ++mt)
#pragma unroll
        for (int dt = 0; dt < 4; ++dt) {
            o[mt][dt] = fzero;
#pragma unroll
            for (int kk = 0; kk < 2; ++kk)
                o[mt][dt] = __builtin_amdgcn_mfma_f32_16x16x32_bf16(
                    pa[mt][kk], bv[dt][kk], o[mt][dt], 0, 0, 0);
        }

    // ---- normalize (+post-softmax mask) and store via LDS for coalescing ----
#pragma unroll
    for (int mt = 0; mt < 2; ++mt)
#pragma unroll
        for (int reg = 0; reg < 4; ++reg) {
            const int r = mt * 16 + l4 * 4 + reg;
            const int t = T0 + wrow0 + r;
            float iv = inv_[mt][reg];
            if (mask[b * 2048 + t] == 0) iv = 0.f;
#pragma unroll
            for (int dt = 0; dt < 4; ++dt) {
                const int d = dt * 16 + l15;
                const int cc = (d >> 3) ^ (r & 7);
                *(u16*)(Pw + r * 128 + cc * 16 + (d & 7) * 2) =
                    f2bf(o[mt][dt][reg] * iv);
            }
        }
#pragma unroll
    for (int it = 0; it < 4; ++it) {
        const int chunk = it * 64 + lane;     // 256 chunks in wave's O tile
        const int r = chunk >> 3, c = chunk & 7;
        const uint4 ov = *(const uint4*)(Pw + r * 128 + ((c ^ (r & 7)) << 4));
        *(uint4*)(Xb + hbase + (size_t)(T0 + wrow0 + r) * 512 + c * 8) = ov;
    }
}

// ---------------------------------------------------------------------------
extern "C" void kernel_launch(void* const* d_in, const int* in_sizes, int n_in,
                              void* d_out, int out_size, void* d_ws, size_t ws_size,
                              hipStream_t stream)
{
    const float* query = (const float*)d_in[0];
    const float* key   = (const float*)d_in[1];
    const float* value = (const float*)d_in[2];
    const int*   mask  = (const int*)d_in[3];
    // d_in[4] = restrict (=31, hard-coded)
    const float* Wq = (const float*)d_in[5];
    const float* bq = (const float*)d_in[6];
    const float* Wk = (const float*)d_in[7];
    const float* bk = (const float*)d_in[8];
    const float* Wv = (const float*)d_in[9];
    const float* bv = (const float*)d_in[10];
    const float* Wo = (const float*)d_in[11];
    const float* bo = (const float*)d_in[12];

    constexpr size_t MSZ = (size_t)8192 * 512;
    u16* wsp = (u16*)d_ws;
    u16* Wt = wsp;
    u16* qc = wsp + 4 * 512 * 512;
    u16* kc = qc + MSZ;
    u16* vc = kc + MSZ;
    u16* Qb = vc + MSZ;
    u16* Kb = Qb + MSZ;
    u16* Vb = Kb + MSZ;
    u16* Xb = qc;  // alias: qc dead after gemm_qkv
    (void)in_sizes; (void)n_in; (void)out_size; (void)ws_size;

    cvt_kernel<<<dim3(1024, 3), 256, 0, stream>>>(query, key, value, qc, kc, vc);
    wtrans_kernel<<<dim3(16, 16, 4), 256, 0, stream>>>(Wq, Wk, Wv, Wo, Wt);
    gemm_qkv_kernel<<<dim3(256, 3), 256, 0, stream>>>(
        qc, kc, vc, Wt, bq, bk, bv, Qb, Kb, Vb);
    attn_kernel<<<512, 256, 0, stream>>>(Qb, Kb, Vb, mask, Xb);
    gemm_out_kernel<<<256, 256, 0, stream>>>(Xb, Wt + 3 * 512 * 512, bo,
                                             (float*)d_out);
}